// Round 7
// baseline (1821.748 us; speedup 1.0000x reference)
//
#include <hip/hip_runtime.h>
#include <hip/hip_bf16.h>

#define T_TOKENS 8192
#define DM 1024
#define DF 4096
#define NE 8
#define NROWS 16384  // T_TOKENS * TOP_K

typedef __attribute__((ext_vector_type(8))) short bf16x8;
typedef __attribute__((ext_vector_type(8))) unsigned short ushort8;
typedef __attribute__((ext_vector_type(4))) float f32x4;

__device__ inline unsigned short f2bf(float f) {
  unsigned int u = __builtin_bit_cast(unsigned int, f);
  u = (u + 0x7fffu + ((u >> 16) & 1u)) >> 16;  // round-to-nearest-even
  return (unsigned short)u;
}

__device__ inline float bf2f(unsigned short s) {
  unsigned int u = ((unsigned int)s) << 16;
  return __builtin_bit_cast(float, u);
}

// async global->LDS, 16 bytes per lane; LDS dest = wave-uniform base + lane*16
__device__ __forceinline__ void gload16(const unsigned short* g, unsigned short* l) {
  __builtin_amdgcn_global_load_lds(
      (const __attribute__((address_space(1))) unsigned int*)g,
      (__attribute__((address_space(3))) unsigned int*)l,
      16, 0, 0);
}

// ---------------- Router: one wave per token; also emits xb (bf16 x) ----------------
__global__ void router_kernel(const float* __restrict__ x,
                              const float* __restrict__ Wr,
                              const float* __restrict__ br,
                              int* __restrict__ ctrl,   // [0..8) counts
                              int* __restrict__ tope,
                              float* __restrict__ topw,
                              unsigned short* __restrict__ xb) {
  const int wid = threadIdx.x >> 6;
  const int lane = threadIdx.x & 63;
  const int t = blockIdx.x * 4 + wid;
  const float* xr = x + (size_t)t * DM;
  unsigned short* xbr = xb + (size_t)t * DM;
  float a[NE];
#pragma unroll
  for (int e = 0; e < NE; ++e) a[e] = 0.f;
#pragma unroll
  for (int it = 0; it < 4; ++it) {
    const int d0 = it * 256 + lane * 4;
    const float4 xv = *(const float4*)(xr + d0);
    ushort4 o;
    o.x = f2bf(xv.x); o.y = f2bf(xv.y); o.z = f2bf(xv.z); o.w = f2bf(xv.w);
    *(ushort4*)(xbr + d0) = o;  // fused x -> bf16 conversion
    const float xs[4] = {xv.x, xv.y, xv.z, xv.w};
#pragma unroll
    for (int j = 0; j < 4; ++j) {
      const float4 wa = *(const float4*)(Wr + (size_t)(d0 + j) * NE);
      const float4 wb = *(const float4*)(Wr + (size_t)(d0 + j) * NE + 4);
      a[0] += xs[j] * wa.x; a[1] += xs[j] * wa.y;
      a[2] += xs[j] * wa.z; a[3] += xs[j] * wa.w;
      a[4] += xs[j] * wb.x; a[5] += xs[j] * wb.y;
      a[6] += xs[j] * wb.z; a[7] += xs[j] * wb.w;
    }
  }
#pragma unroll
  for (int off = 32; off > 0; off >>= 1) {
#pragma unroll
    for (int e = 0; e < NE; ++e) a[e] += __shfl_xor(a[e], off);
  }
  if (lane == 0) {
    float lg[NE];
    float m = -1e30f;
#pragma unroll
    for (int e = 0; e < NE; ++e) { lg[e] = a[e] + br[e]; m = fmaxf(m, lg[e]); }
    float p[NE];
#pragma unroll
    for (int e = 0; e < NE; ++e) p[e] = expf(lg[e] - m);
    int i0 = 0;
#pragma unroll
    for (int e = 1; e < NE; ++e) if (p[e] > p[i0]) i0 = e;
    int i1 = (i0 == 0) ? 1 : 0;
#pragma unroll
    for (int e = 0; e < NE; ++e) if (e != i0 && p[e] > p[i1]) i1 = e;
    const float s = p[i0] + p[i1];
    tope[2 * t] = i0;
    tope[2 * t + 1] = i1;
    topw[2 * t] = p[i0] / s;
    topw[2 * t + 1] = p[i1] / s;
    atomicAdd(&ctrl[i0], 1);
    atomicAdd(&ctrl[i1], 1);
  }
}

// ---------------- Scan: offsets + cursors ----------------
__global__ void scan_kernel(int* __restrict__ ctrl) {
  if (threadIdx.x == 0 && blockIdx.x == 0) {
    int off = 0;
    for (int e = 0; e < NE; ++e) {
      ctrl[8 + e] = off;    // offsets
      ctrl[20 + e] = off;   // cursors
      off += ctrl[e];
    }
    ctrl[16] = off;
  }
}

// ---------------- Place: compact row lists + inverse map ----------------
__global__ void place_kernel(const int* __restrict__ tope,
                             const float* __restrict__ topw,
                             int* __restrict__ ctrl,
                             int* __restrict__ rowlist,
                             float* __restrict__ roww,
                             int* __restrict__ posmap) {
  const int t = blockIdx.x * blockDim.x + threadIdx.x;
#pragma unroll
  for (int k = 0; k < 2; ++k) {
    const int e = tope[2 * t + k];
    const int pos = atomicAdd(&ctrl[20 + e], 1);
    rowlist[pos] = t;
    roww[pos] = topw[2 * t + k];
    posmap[2 * t + k] = pos;
  }
}

// ---------------- Transpose-convert: in [E][R][C] fp32 -> out [E][C][R] bf16 ----
// Vectorized: float4 reads, ushort8 (16B) writes. LDS bank patterns are 2-way max.
__global__ void transpose_cvt_kernel(const float* __restrict__ in,
                                     unsigned short* __restrict__ outp,
                                     int R, int C) {
  __shared__ float tile[64][65];
  const int e = blockIdx.z;
  const int r0 = blockIdx.y * 64;
  const int c0 = blockIdx.x * 64;
  const float* src = in + ((size_t)e * R + r0) * C + c0;
  const int tid = threadIdx.x;
  const int rr0 = tid >> 4;        // 0..15
  const int cc4 = (tid & 15) * 4;  // 0..60
#pragma unroll
  for (int i = 0; i < 4; ++i) {
    const int rr = rr0 + i * 16;
    const float4 v = *(const float4*)(src + (size_t)rr * C + cc4);
    tile[rr][cc4] = v.x; tile[rr][cc4 + 1] = v.y;
    tile[rr][cc4 + 2] = v.z; tile[rr][cc4 + 3] = v.w;
  }
  __syncthreads();
  unsigned short* dst = outp + ((size_t)e * C + c0) * R + r0;
  const int orr = (tid & 7) * 8;   // 0..56 (output col = original r)
  const int oc0 = tid >> 3;        // 0..31 (output row = original c)
#pragma unroll
  for (int i = 0; i < 2; ++i) {
    const int oc = oc0 + i * 32;
    ushort8 o;
#pragma unroll
    for (int j = 0; j < 8; ++j) o[j] = f2bf(tile[orr + j][oc]);
    *(ushort8*)(dst + (size_t)oc * R + orr) = o;
  }
}

// ---------------- GEMM1: h = gelu(x[rows] @ W1[e] + b1[e]) ----------------
// EXACT round-4 measured-best kernel (283 us): 128x128, single-buffer, T2 swizzle,
// swapped MFMA, direct ushort4 epilogue with libm erff, (256,4),
// grid x=n-tile / y=mt. NOTE: fast inline gelu regressed this kernel twice
// (R5/R6: +72us, WRITE 335->620+ MB) -- epilogue pacing matters; keep erff.
__global__ __launch_bounds__(256, 4) void gemm1_kernel(
    const unsigned short* __restrict__ xb,   // [T][DM]
    const unsigned short* __restrict__ w1t,  // [E][DF][DM]
    const float* __restrict__ b1,            // [E][DF]
    const int* __restrict__ ctrl,
    const int* __restrict__ rowlist,
    unsigned short* __restrict__ h) {        // [NROWS][DF]
  const int e = blockIdx.z;
  const int count = ctrl[e];
  const int mt = blockIdx.y;
  if (mt * 128 >= count) return;
  const int off = ctrl[8 + e];
  const int n0 = blockIdx.x * 128;
  const int tid = threadIdx.x;
  const int wid = tid >> 6;
  const int lane = tid & 63;
  const int wm = (wid & 1) * 64;
  const int wn = (wid >> 1) * 64;
  const int q = lane >> 4;
  const int l16 = lane & 15;
  const int rl = lane >> 3;   // 0..7 (row within 8-row stage slab)
  const int ch = lane & 7;    // 16B chunk within 64-elt row
  const int sch = ch ^ rl;    // swizzled source chunk (involution)

  __shared__ __attribute__((aligned(16))) unsigned short lA[128 * 64];
  __shared__ __attribute__((aligned(16))) unsigned short lB[128 * 64];

  const unsigned short* aBase[4];
  const unsigned short* bBase[4];
  unsigned short* lABase[4];
  unsigned short* lBBase[4];
#pragma unroll
  for (int i = 0; i < 4; ++i) {
    const int r = wid * 32 + i * 8 + rl;   // tile row 0..127
    int rr = mt * 128 + r;
    if (rr >= count) rr = count - 1;       // expert-local clamp
    const int tok = rowlist[off + rr];
    aBase[i] = xb + (size_t)tok * DM + sch * 8;
    bBase[i] = w1t + ((size_t)e * DF + n0 + r) * DM + sch * 8;
    lABase[i] = &lA[(wid * 32 + i * 8) * 64];  // wave-uniform, linear dest
    lBBase[i] = &lB[(wid * 32 + i * 8) * 64];
  }

  f32x4 acc[4][4];
  const f32x4 z = {0.f, 0.f, 0.f, 0.f};
#pragma unroll
  for (int im = 0; im < 4; ++im)
#pragma unroll
    for (int in = 0; in < 4; ++in) acc[im][in] = z;

  for (int k0 = 0; k0 < DM; k0 += 64) {
#pragma unroll
    for (int i = 0; i < 4; ++i) gload16(aBase[i] + k0, lABase[i]);
#pragma unroll
    for (int i = 0; i < 4; ++i) gload16(bBase[i] + k0, lBBase[i]);
    __syncthreads();
#pragma unroll
    for (int ks = 0; ks < 2; ++ks) {
      const int pc = ((ks * 4 + q) ^ (l16 & 7)) * 8;  // swizzled chunk on read
      bf16x8 af[4], bfr[4];
#pragma unroll
      for (int im = 0; im < 4; ++im)
        af[im] = *(const bf16x8*)&lA[(wm + im * 16 + l16) * 64 + pc];
#pragma unroll
      for (int in = 0; in < 4; ++in)
        bfr[in] = *(const bf16x8*)&lB[(wn + in * 16 + l16) * 64 + pc];
#pragma unroll
      for (int im = 0; im < 4; ++im)
#pragma unroll
        for (int in = 0; in < 4; ++in)
          acc[im][in] = __builtin_amdgcn_mfma_f32_16x16x32_bf16(
              bfr[in], af[im], acc[im][in], 0, 0, 0);  // swapped: lane=row, elems=cols
    }
    __syncthreads();
  }

  // Epilogue: lane l16 holds row m = wm+im*16+l16; acc elems = cols wn+in*16+q*4+[0..3]
#pragma unroll
  for (int im = 0; im < 4; ++im) {
    const int r = mt * 128 + wm + im * 16 + l16;
    if (r < count) {
      unsigned short* hrow = h + ((size_t)(off + r)) * DF + n0 + wn + q * 4;
#pragma unroll
      for (int in = 0; in < 4; ++in) {
        const float4 bv = *(const float4*)(b1 + (size_t)e * DF + n0 + wn + in * 16 + q * 4);
        float v0 = acc[im][in][0] + bv.x;
        float v1 = acc[im][in][1] + bv.y;
        float v2 = acc[im][in][2] + bv.z;
        float v3 = acc[im][in][3] + bv.w;
        ushort4 o;
        o.x = f2bf(0.5f * v0 * (1.0f + erff(v0 * 0.70710678118f)));
        o.y = f2bf(0.5f * v1 * (1.0f + erff(v1 * 0.70710678118f)));
        o.z = f2bf(0.5f * v2 * (1.0f + erff(v2 * 0.70710678118f)));
        o.w = f2bf(0.5f * v3 * (1.0f + erff(v3 * 0.70710678118f)));
        *(ushort4*)(hrow + in * 16) = o;
      }
    }
  }
}

// ---------------- GEMM2: y[row] = h[row] @ W2[e] + b2[e] ----------------
// Round-4 config (BM=128, BN=256, single-buffer, 48 KB LDS, grid x=mt).
// ONLY change this round: __launch_bounds__(256,3) -- 48 KB LDS admits
// 3 blocks/CU (144<=160 KB) and VGPR ~164 fits the 512/3=170 budget;
// +50% TLP to hide the stage drain (m114 implicit wave overlap).
__global__ __launch_bounds__(256, 3) void gemm2_kernel(
    const unsigned short* __restrict__ h,    // [NROWS][DF]
    const unsigned short* __restrict__ w2t,  // [E][DM][DF]
    const float* __restrict__ b2,            // [E][DM]
    const int* __restrict__ ctrl,
    unsigned short* __restrict__ y) {        // [NROWS][DM] bf16, bias folded
  const int e = blockIdx.z;
  const int count = ctrl[e];
  const int mt = blockIdx.x;
  if (mt * 128 >= count) return;
  const int off = ctrl[8 + e];
  const int n0 = blockIdx.y * 256;
  const int tid = threadIdx.x;
  const int wid = tid >> 6;
  const int lane = tid & 63;
  const int wm = (wid & 1) * 64;
  const int wn = (wid >> 1) * 128;   // 2x2 waves over 128x256
  const int q = lane >> 4;
  const int l16 = lane & 15;
  const int rl = lane >> 3;
  const int ch = lane & 7;
  const int sch = ch ^ rl;    // swizzled source chunk

  __shared__ __attribute__((aligned(16))) unsigned short lA[128 * 64];
  __shared__ __attribute__((aligned(16))) unsigned short lB[256 * 64];

  const unsigned short* aBase[4];
  const unsigned short* bBase[8];
  unsigned short* lABase[4];
  unsigned short* lBBase[8];
#pragma unroll
  for (int i = 0; i < 4; ++i) {
    const int r = wid * 32 + i * 8 + rl;
    int rr = mt * 128 + r;
    if (rr >= count) rr = count - 1;       // expert-local clamp (h written there)
    aBase[i] = h + (size_t)(off + rr) * DF + sch * 8;
    lABase[i] = &lA[(wid * 32 + i * 8) * 64];
  }
#pragma unroll
  for (int i = 0; i < 8; ++i) {
    const int r = wid * 64 + i * 8 + rl;   // 0..255
    bBase[i] = w2t + ((size_t)e * DM + n0 + r) * DF + sch * 8;
    lBBase[i] = &lB[(wid * 64 + i * 8) * 64];
  }

  f32x4 acc[4][8];
  const f32x4 z = {0.f, 0.f, 0.f, 0.f};
#pragma unroll
  for (int im = 0; im < 4; ++im)
#pragma unroll
    for (int in = 0; in < 8; ++in) acc[im][in] = z;

  for (int k0 = 0; k0 < DF; k0 += 64) {
#pragma unroll
    for (int i = 0; i < 4; ++i) gload16(aBase[i] + k0, lABase[i]);
#pragma unroll
    for (int i = 0; i < 8; ++i) gload16(bBase[i] + k0, lBBase[i]);
    __syncthreads();
#pragma unroll
    for (int ks = 0; ks < 2; ++ks) {
      const int pc = ((ks * 4 + q) ^ (l16 & 7)) * 8;
      bf16x8 af[4], bfr[8];
#pragma unroll
      for (int im = 0; im < 4; ++im)
        af[im] = *(const bf16x8*)&lA[(wm + im * 16 + l16) * 64 + pc];
#pragma unroll
      for (int in = 0; in < 8; ++in)
        bfr[in] = *(const bf16x8*)&lB[(wn + in * 16 + l16) * 64 + pc];
#pragma unroll
      for (int im = 0; im < 4; ++im)
#pragma unroll
        for (int in = 0; in < 8; ++in)
          acc[im][in] = __builtin_amdgcn_mfma_f32_16x16x32_bf16(
              bfr[in], af[im], acc[im][in], 0, 0, 0);  // swapped
    }
    __syncthreads();
  }

#pragma unroll
  for (int im = 0; im < 4; ++im) {
    const int r = mt * 128 + wm + im * 16 + l16;
    if (r < count) {
      unsigned short* yrow = y + ((size_t)(off + r)) * DM + n0 + wn + q * 4;
#pragma unroll
      for (int in = 0; in < 8; ++in) {
        const float4 bv = *(const float4*)(b2 + (size_t)e * DM + n0 + wn + in * 16 + q * 4);
        ushort4 o;
        o.x = f2bf(acc[im][in][0] + bv.x);
        o.y = f2bf(acc[im][in][1] + bv.y);
        o.z = f2bf(acc[im][in][2] + bv.z);
        o.w = f2bf(acc[im][in][3] + bv.w);
        *(ushort4*)(yrow + in * 16) = o;
      }
    }
  }
}

// ---------------- Combine: out[t] = w0*y[p0] + w1*y[p1] ----------------
__global__ void combine_kernel(const unsigned short* __restrict__ y,
                               const int* __restrict__ posmap,
                               const float* __restrict__ topw,
                               float* __restrict__ out) {
  const int t = blockIdx.x;
  const int c = threadIdx.x * 4;
  const int p0 = posmap[2 * t];
  const int p1 = posmap[2 * t + 1];
  const float w0 = topw[2 * t];
  const float w1 = topw[2 * t + 1];
  const ushort4 a = *(const ushort4*)(y + (size_t)p0 * DM + c);
  const ushort4 b = *(const ushort4*)(y + (size_t)p1 * DM + c);
  float4 o;
  o.x = w0 * bf2f(a.x) + w1 * bf2f(b.x);
  o.y = w0 * bf2f(a.y) + w1 * bf2f(b.y);
  o.z = w0 * bf2f(a.z) + w1 * bf2f(b.z);
  o.w = w0 * bf2f(a.w) + w1 * bf2f(b.w);
  *(float4*)(out + (size_t)t * DM + c) = o;
}

extern "C" void kernel_launch(void* const* d_in, const int* in_sizes, int n_in,
                              void* d_out, int out_size, void* d_ws, size_t ws_size,
                              hipStream_t stream) {
  const float* x  = (const float*)d_in[0];
  const float* Wr = (const float*)d_in[1];
  const float* br = (const float*)d_in[2];
  const float* W1 = (const float*)d_in[3];
  const float* b1 = (const float*)d_in[4];
  const float* W2 = (const float*)d_in[5];
  const float* b2 = (const float*)d_in[6];
  float* out = (float*)d_out;

  char* p = (char*)d_ws;
  auto alloc = [&](size_t bytes) -> char* {
    char* r = p;
    p += (bytes + 255) & ~(size_t)255;
    return r;
  };
  int* ctrl = (int*)alloc(1024);
  int* tope = (int*)alloc((size_t)2 * T_TOKENS * 4);
  float* topw = (float*)alloc((size_t)2 * T_TOKENS * 4);
  int* rowlist = (int*)alloc((size_t)NROWS * 4);
  float* roww = (float*)alloc((size_t)NROWS * 4);
  int* posmap = (int*)alloc((size_t)NROWS * 4);
  unsigned short* xb  = (unsigned short*)alloc((size_t)T_TOKENS * DM * 2);
  unsigned short* w1t = (unsigned short*)alloc((size_t)NE * DF * DM * 2);
  unsigned short* w2t = (unsigned short*)alloc((size_t)NE * DM * DF * 2);
  unsigned short* h   = (unsigned short*)alloc((size_t)NROWS * DF * 2);
  if ((size_t)(p - (char*)d_ws) > ws_size) return;  // insufficient workspace

  // y_rows aliases w1t: w1t is only read by gemm1, which completes before
  // gemm2 writes y (same stream). 33.5 MB <= 67 MB region.
  unsigned short* y = w1t;

  hipMemsetAsync(ctrl, 0, 1024, stream);

  router_kernel<<<T_TOKENS / 4, 256, 0, stream>>>(x, Wr, br, ctrl, tope, topw, xb);
  scan_kernel<<<1, 64, 0, stream>>>(ctrl);
  place_kernel<<<T_TOKENS / 256, 256, 0, stream>>>(tope, topw, ctrl, rowlist, roww, posmap);
  transpose_cvt_kernel<<<dim3(DF / 64, DM / 64, NE), 256, 0, stream>>>(W1, w1t, DM, DF);
  transpose_cvt_kernel<<<dim3(DM / 64, DF / 64, NE), 256, 0, stream>>>(W2, w2t, DF, DM);
  gemm1_kernel<<<dim3(DF / 128, 64, NE), 256, 0, stream>>>(xb, w1t, b1, ctrl, rowlist, h);
  gemm2_kernel<<<dim3(64, DM / 256, NE), 256, 0, stream>>>(h, w2t, b2, ctrl, y);
  combine_kernel<<<T_TOKENS, 256, 0, stream>>>(y, posmap, topw, out);
}

// Round 8
// 1042.913 us; speedup vs baseline: 1.7468x; 1.7468x over previous
//
#include <hip/hip_runtime.h>
#include <hip/hip_bf16.h>

#define T_TOKENS 8192
#define DM 1024
#define DF 4096
#define NE 8
#define NROWS 16384  // T_TOKENS * TOP_K

typedef __attribute__((ext_vector_type(8))) short bf16x8;
typedef __attribute__((ext_vector_type(8))) unsigned short ushort8;
typedef __attribute__((ext_vector_type(4))) float f32x4;

__device__ inline unsigned short f2bf(float f) {
  unsigned int u = __builtin_bit_cast(unsigned int, f);
  u = (u + 0x7fffu + ((u >> 16) & 1u)) >> 16;  // round-to-nearest-even
  return (unsigned short)u;
}

__device__ inline float bf2f(unsigned short s) {
  unsigned int u = ((unsigned int)s) << 16;
  return __builtin_bit_cast(float, u);
}

// async global->LDS, 16 bytes per lane; LDS dest = wave-uniform base + lane*16
__device__ __forceinline__ void gload16(const unsigned short* g, unsigned short* l) {
  __builtin_amdgcn_global_load_lds(
      (const __attribute__((address_space(1))) unsigned int*)g,
      (__attribute__((address_space(3))) unsigned int*)l,
      16, 0, 0);
}

// ---------------- Fused setup: router (blocks 0..2047) + transpose W1
// (blocks 2048..10239) + transpose W2 (blocks 10240..18431). The three are
// independent; one dispatch removes two graph-node boundaries and overlaps
// router's read-bound blocks with the transposes' write-bound blocks.
__global__ __launch_bounds__(256) void setup_kernel(
    const float* __restrict__ x, const float* __restrict__ Wr,
    const float* __restrict__ br, int* __restrict__ ctrl,
    int* __restrict__ tope, float* __restrict__ topw,
    unsigned short* __restrict__ xb,
    const float* __restrict__ W1, const float* __restrict__ W2,
    unsigned short* __restrict__ w1t, unsigned short* __restrict__ w2t) {
  __shared__ float tile[64][65];  // used by transpose sections only
  const int bx = blockIdx.x;
  const int tid = threadIdx.x;

  if (bx < 2048) {
    // ---- router: one wave per token; also emits xb (bf16 x) ----
    const int wid = tid >> 6;
    const int lane = tid & 63;
    const int t = bx * 4 + wid;
    const float* xr = x + (size_t)t * DM;
    unsigned short* xbr = xb + (size_t)t * DM;
    float a[NE];
#pragma unroll
    for (int e = 0; e < NE; ++e) a[e] = 0.f;
#pragma unroll
    for (int it = 0; it < 4; ++it) {
      const int d0 = it * 256 + lane * 4;
      const float4 xv = *(const float4*)(xr + d0);
      ushort4 o;
      o.x = f2bf(xv.x); o.y = f2bf(xv.y); o.z = f2bf(xv.z); o.w = f2bf(xv.w);
      *(ushort4*)(xbr + d0) = o;  // fused x -> bf16 conversion
      const float xs[4] = {xv.x, xv.y, xv.z, xv.w};
#pragma unroll
      for (int j = 0; j < 4; ++j) {
        const float4 wa = *(const float4*)(Wr + (size_t)(d0 + j) * NE);
        const float4 wb = *(const float4*)(Wr + (size_t)(d0 + j) * NE + 4);
        a[0] += xs[j] * wa.x; a[1] += xs[j] * wa.y;
        a[2] += xs[j] * wa.z; a[3] += xs[j] * wa.w;
        a[4] += xs[j] * wb.x; a[5] += xs[j] * wb.y;
        a[6] += xs[j] * wb.z; a[7] += xs[j] * wb.w;
      }
    }
#pragma unroll
    for (int off = 32; off > 0; off >>= 1) {
#pragma unroll
      for (int e = 0; e < NE; ++e) a[e] += __shfl_xor(a[e], off);
    }
    if (lane == 0) {
      float lg[NE];
      float m = -1e30f;
#pragma unroll
      for (int e = 0; e < NE; ++e) { lg[e] = a[e] + br[e]; m = fmaxf(m, lg[e]); }
      float p[NE];
#pragma unroll
      for (int e = 0; e < NE; ++e) p[e] = expf(lg[e] - m);
      int i0 = 0;
#pragma unroll
      for (int e = 1; e < NE; ++e) if (p[e] > p[i0]) i0 = e;
      int i1 = (i0 == 0) ? 1 : 0;
#pragma unroll
      for (int e = 0; e < NE; ++e) if (e != i0 && p[e] > p[i1]) i1 = e;
      const float s = p[i0] + p[i1];
      tope[2 * t] = i0;
      tope[2 * t + 1] = i1;
      topw[2 * t] = p[i0] / s;
      topw[2 * t + 1] = p[i1] / s;
      atomicAdd(&ctrl[i0], 1);
      atomicAdd(&ctrl[i1], 1);
    }
  } else {
    // ---- transpose-convert: in [E][R][C] fp32 -> out [E][C][R] bf16 ----
    const float* in;
    unsigned short* outp;
    int R, C, r0, c0, e;
    if (bx < 2048 + 8192) {
      const int idx = bx - 2048;           // W1: R=DM, C=DF; 64x16 tiles/expert
      e = idx >> 10;
      const int t2 = idx & 1023;
      c0 = (t2 & 63) * 64;
      r0 = (t2 >> 6) * 64;
      in = W1; outp = w1t; R = DM; C = DF;
    } else {
      const int idx = bx - 10240;          // W2: R=DF, C=DM; 16x64 tiles/expert
      e = idx >> 10;
      const int t2 = idx & 1023;
      c0 = (t2 & 15) * 64;
      r0 = (t2 >> 4) * 64;
      in = W2; outp = w2t; R = DF; C = DM;
    }
    const float* src = in + ((size_t)e * R + r0) * C + c0;
    const int rr0 = tid >> 4;        // 0..15
    const int cc4 = (tid & 15) * 4;  // 0..60
#pragma unroll
    for (int i = 0; i < 4; ++i) {
      const int rr = rr0 + i * 16;
      const float4 v = *(const float4*)(src + (size_t)rr * C + cc4);
      tile[rr][cc4] = v.x; tile[rr][cc4 + 1] = v.y;
      tile[rr][cc4 + 2] = v.z; tile[rr][cc4 + 3] = v.w;
    }
    __syncthreads();
    unsigned short* dst = outp + ((size_t)e * C + c0) * R + r0;
    const int orr = (tid & 7) * 8;   // 0..56 (output col = original r)
    const int oc0 = tid >> 3;        // 0..31 (output row = original c)
#pragma unroll
    for (int i = 0; i < 2; ++i) {
      const int oc = oc0 + i * 32;
      ushort8 o;
#pragma unroll
      for (int j = 0; j < 8; ++j) o[j] = f2bf(tile[orr + j][oc]);
      *(ushort8*)(dst + (size_t)oc * R + orr) = o;
    }
  }
}

// ---------------- Place: compact row lists + inverse map ----------------
// Offsets computed inline from counts (scan_kernel deleted); cursors
// ctrl[20..27] start at 0 (memset) and are biased by the computed offset.
__global__ void place_kernel(const int* __restrict__ tope,
                             const float* __restrict__ topw,
                             int* __restrict__ ctrl,
                             int* __restrict__ rowlist,
                             int* __restrict__ posmap) {
  const int t = blockIdx.x * blockDim.x + threadIdx.x;
#pragma unroll
  for (int k = 0; k < 2; ++k) {
    const int e = tope[2 * t + k];
    int off = 0;
    for (int i = 0; i < e; ++i) off += ctrl[i];
    const int pos = off + atomicAdd(&ctrl[20 + e], 1);
    rowlist[pos] = t;
    posmap[2 * t + k] = pos;
  }
}

// ---------------- GEMM1: h = gelu(x[rows] @ W1[e] + b1[e]) ----------------
// EXACT round-4 measured-best config (283 us): 128x128, single-buffer, T2
// swizzle, swapped MFMA, direct ushort4 epilogue with libm erff, (256,4),
// grid x=n-tile / y=mt. (Fast inline gelu regressed twice: R5/R6 +72us,
// WRITE 335->620+ MB -- epilogue pacing matters; keep erff.)
__global__ __launch_bounds__(256, 4) void gemm1_kernel(
    const unsigned short* __restrict__ xb,   // [T][DM]
    const unsigned short* __restrict__ w1t,  // [E][DF][DM]
    const float* __restrict__ b1,            // [E][DF]
    const int* __restrict__ ctrl,
    const int* __restrict__ rowlist,
    unsigned short* __restrict__ h) {        // [NROWS][DF]
  const int e = blockIdx.z;
  const int count = ctrl[e];
  const int mt = blockIdx.y;
  if (mt * 128 >= count) return;
  int off = 0;
  for (int i = 0; i < e; ++i) off += ctrl[i];  // inline prefix (uniform e)
  const int n0 = blockIdx.x * 128;
  const int tid = threadIdx.x;
  const int wid = tid >> 6;
  const int lane = tid & 63;
  const int wm = (wid & 1) * 64;
  const int wn = (wid >> 1) * 64;
  const int q = lane >> 4;
  const int l16 = lane & 15;
  const int rl = lane >> 3;   // 0..7 (row within 8-row stage slab)
  const int ch = lane & 7;    // 16B chunk within 64-elt row
  const int sch = ch ^ rl;    // swizzled source chunk (involution)

  __shared__ __attribute__((aligned(16))) unsigned short lA[128 * 64];
  __shared__ __attribute__((aligned(16))) unsigned short lB[128 * 64];

  const unsigned short* aBase[4];
  const unsigned short* bBase[4];
  unsigned short* lABase[4];
  unsigned short* lBBase[4];
#pragma unroll
  for (int i = 0; i < 4; ++i) {
    const int r = wid * 32 + i * 8 + rl;   // tile row 0..127
    int rr = mt * 128 + r;
    if (rr >= count) rr = count - 1;       // expert-local clamp
    const int tok = rowlist[off + rr];
    aBase[i] = xb + (size_t)tok * DM + sch * 8;
    bBase[i] = w1t + ((size_t)e * DF + n0 + r) * DM + sch * 8;
    lABase[i] = &lA[(wid * 32 + i * 8) * 64];  // wave-uniform, linear dest
    lBBase[i] = &lB[(wid * 32 + i * 8) * 64];
  }

  f32x4 acc[4][4];
  const f32x4 z = {0.f, 0.f, 0.f, 0.f};
#pragma unroll
  for (int im = 0; im < 4; ++im)
#pragma unroll
    for (int in = 0; in < 4; ++in) acc[im][in] = z;

  for (int k0 = 0; k0 < DM; k0 += 64) {
#pragma unroll
    for (int i = 0; i < 4; ++i) gload16(aBase[i] + k0, lABase[i]);
#pragma unroll
    for (int i = 0; i < 4; ++i) gload16(bBase[i] + k0, lBBase[i]);
    __syncthreads();
#pragma unroll
    for (int ks = 0; ks < 2; ++ks) {
      const int pc = ((ks * 4 + q) ^ (l16 & 7)) * 8;  // swizzled chunk on read
      bf16x8 af[4], bfr[4];
#pragma unroll
      for (int im = 0; im < 4; ++im)
        af[im] = *(const bf16x8*)&lA[(wm + im * 16 + l16) * 64 + pc];
#pragma unroll
      for (int in = 0; in < 4; ++in)
        bfr[in] = *(const bf16x8*)&lB[(wn + in * 16 + l16) * 64 + pc];
#pragma unroll
      for (int im = 0; im < 4; ++im)
#pragma unroll
        for (int in = 0; in < 4; ++in)
          acc[im][in] = __builtin_amdgcn_mfma_f32_16x16x32_bf16(
              bfr[in], af[im], acc[im][in], 0, 0, 0);  // swapped: lane=row, elems=cols
    }
    __syncthreads();
  }

  // Epilogue: lane l16 holds row m = wm+im*16+l16; acc elems = cols wn+in*16+q*4+[0..3]
#pragma unroll
  for (int im = 0; im < 4; ++im) {
    const int r = mt * 128 + wm + im * 16 + l16;
    if (r < count) {
      unsigned short* hrow = h + ((size_t)(off + r)) * DF + n0 + wn + q * 4;
#pragma unroll
      for (int in = 0; in < 4; ++in) {
        const float4 bv = *(const float4*)(b1 + (size_t)e * DF + n0 + wn + in * 16 + q * 4);
        float v0 = acc[im][in][0] + bv.x;
        float v1 = acc[im][in][1] + bv.y;
        float v2 = acc[im][in][2] + bv.z;
        float v3 = acc[im][in][3] + bv.w;
        ushort4 o;
        o.x = f2bf(0.5f * v0 * (1.0f + erff(v0 * 0.70710678118f)));
        o.y = f2bf(0.5f * v1 * (1.0f + erff(v1 * 0.70710678118f)));
        o.z = f2bf(0.5f * v2 * (1.0f + erff(v2 * 0.70710678118f)));
        o.w = f2bf(0.5f * v3 * (1.0f + erff(v3 * 0.70710678118f)));
        *(ushort4*)(hrow + in * 16) = o;
      }
    }
  }
}

// ---------------- GEMM2: y[row] = h[row] @ W2[e] + b2[e] ----------------
// EXACT round-4 config (283 us): BM=128, BN=256, single-buffer, 48 KB LDS,
// (256,2), grid x=mt. (R7's (256,3) spilled acc to scratch: VGPR 164->84,
// WRITE 1 GB, 3.5x slower. Never tighten bounds near the acc VGPR budget.)
__global__ __launch_bounds__(256, 2) void gemm2_kernel(
    const unsigned short* __restrict__ h,    // [NROWS][DF]
    const unsigned short* __restrict__ w2t,  // [E][DM][DF]
    const float* __restrict__ b2,            // [E][DM]
    const int* __restrict__ ctrl,
    unsigned short* __restrict__ y) {        // [NROWS][DM] bf16, bias folded
  const int e = blockIdx.z;
  const int count = ctrl[e];
  const int mt = blockIdx.x;
  if (mt * 128 >= count) return;
  int off = 0;
  for (int i = 0; i < e; ++i) off += ctrl[i];  // inline prefix (uniform e)
  const int n0 = blockIdx.y * 256;
  const int tid = threadIdx.x;
  const int wid = tid >> 6;
  const int lane = tid & 63;
  const int wm = (wid & 1) * 64;
  const int wn = (wid >> 1) * 128;   // 2x2 waves over 128x256
  const int q = lane >> 4;
  const int l16 = lane & 15;
  const int rl = lane >> 3;
  const int ch = lane & 7;
  const int sch = ch ^ rl;    // swizzled source chunk

  __shared__ __attribute__((aligned(16))) unsigned short lA[128 * 64];
  __shared__ __attribute__((aligned(16))) unsigned short lB[256 * 64];

  const unsigned short* aBase[4];
  const unsigned short* bBase[8];
  unsigned short* lABase[4];
  unsigned short* lBBase[8];
#pragma unroll
  for (int i = 0; i < 4; ++i) {
    const int r = wid * 32 + i * 8 + rl;
    int rr = mt * 128 + r;
    if (rr >= count) rr = count - 1;       // expert-local clamp (h written there)
    aBase[i] = h + (size_t)(off + rr) * DF + sch * 8;
    lABase[i] = &lA[(wid * 32 + i * 8) * 64];
  }
#pragma unroll
  for (int i = 0; i < 8; ++i) {
    const int r = wid * 64 + i * 8 + rl;   // 0..255
    bBase[i] = w2t + ((size_t)e * DM + n0 + r) * DF + sch * 8;
    lBBase[i] = &lB[(wid * 64 + i * 8) * 64];
  }

  f32x4 acc[4][8];
  const f32x4 z = {0.f, 0.f, 0.f, 0.f};
#pragma unroll
  for (int im = 0; im < 4; ++im)
#pragma unroll
    for (int in = 0; in < 8; ++in) acc[im][in] = z;

  for (int k0 = 0; k0 < DF; k0 += 64) {
#pragma unroll
    for (int i = 0; i < 4; ++i) gload16(aBase[i] + k0, lABase[i]);
#pragma unroll
    for (int i = 0; i < 8; ++i) gload16(bBase[i] + k0, lBBase[i]);
    __syncthreads();
#pragma unroll
    for (int ks = 0; ks < 2; ++ks) {
      const int pc = ((ks * 4 + q) ^ (l16 & 7)) * 8;
      bf16x8 af[4], bfr[8];
#pragma unroll
      for (int im = 0; im < 4; ++im)
        af[im] = *(const bf16x8*)&lA[(wm + im * 16 + l16) * 64 + pc];
#pragma unroll
      for (int in = 0; in < 8; ++in)
        bfr[in] = *(const bf16x8*)&lB[(wn + in * 16 + l16) * 64 + pc];
#pragma unroll
      for (int im = 0; im < 4; ++im)
#pragma unroll
        for (int in = 0; in < 8; ++in)
          acc[im][in] = __builtin_amdgcn_mfma_f32_16x16x32_bf16(
              bfr[in], af[im], acc[im][in], 0, 0, 0);  // swapped
    }
    __syncthreads();
  }

#pragma unroll
  for (int im = 0; im < 4; ++im) {
    const int r = mt * 128 + wm + im * 16 + l16;
    if (r < count) {
      unsigned short* yrow = y + ((size_t)(off + r)) * DM + n0 + wn + q * 4;
#pragma unroll
      for (int in = 0; in < 8; ++in) {
        const float4 bv = *(const float4*)(b2 + (size_t)e * DM + n0 + wn + in * 16 + q * 4);
        ushort4 o;
        o.x = f2bf(acc[im][in][0] + bv.x);
        o.y = f2bf(acc[im][in][1] + bv.y);
        o.z = f2bf(acc[im][in][2] + bv.z);
        o.w = f2bf(acc[im][in][3] + bv.w);
        *(ushort4*)(yrow + in * 16) = o;
      }
    }
  }
}

// ---------------- Combine: out[t] = w0*y[p0] + w1*y[p1] ----------------
__global__ void combine_kernel(const unsigned short* __restrict__ y,
                               const int* __restrict__ posmap,
                               const float* __restrict__ topw,
                               float* __restrict__ out) {
  const int t = blockIdx.x;
  const int c = threadIdx.x * 4;
  const int p0 = posmap[2 * t];
  const int p1 = posmap[2 * t + 1];
  const float w0 = topw[2 * t];
  const float w1 = topw[2 * t + 1];
  const ushort4 a = *(const ushort4*)(y + (size_t)p0 * DM + c);
  const ushort4 b = *(const ushort4*)(y + (size_t)p1 * DM + c);
  float4 o;
  o.x = w0 * bf2f(a.x) + w1 * bf2f(b.x);
  o.y = w0 * bf2f(a.y) + w1 * bf2f(b.y);
  o.z = w0 * bf2f(a.z) + w1 * bf2f(b.z);
  o.w = w0 * bf2f(a.w) + w1 * bf2f(b.w);
  *(float4*)(out + (size_t)t * DM + c) = o;
}

extern "C" void kernel_launch(void* const* d_in, const int* in_sizes, int n_in,
                              void* d_out, int out_size, void* d_ws, size_t ws_size,
                              hipStream_t stream) {
  const float* x  = (const float*)d_in[0];
  const float* Wr = (const float*)d_in[1];
  const float* br = (const float*)d_in[2];
  const float* W1 = (const float*)d_in[3];
  const float* b1 = (const float*)d_in[4];
  const float* W2 = (const float*)d_in[5];
  const float* b2 = (const float*)d_in[6];
  float* out = (float*)d_out;

  char* p = (char*)d_ws;
  auto alloc = [&](size_t bytes) -> char* {
    char* r = p;
    p += (bytes + 255) & ~(size_t)255;
    return r;
  };
  int* ctrl = (int*)alloc(1024);
  int* tope = (int*)alloc((size_t)2 * T_TOKENS * 4);
  float* topw = (float*)alloc((size_t)2 * T_TOKENS * 4);
  int* rowlist = (int*)alloc((size_t)NROWS * 4);
  int* posmap = (int*)alloc((size_t)NROWS * 4);
  unsigned short* xb  = (unsigned short*)alloc((size_t)T_TOKENS * DM * 2);
  unsigned short* w1t = (unsigned short*)alloc((size_t)NE * DF * DM * 2);
  unsigned short* w2t = (unsigned short*)alloc((size_t)NE * DM * DF * 2);
  unsigned short* h   = (unsigned short*)alloc((size_t)NROWS * DF * 2);
  if ((size_t)(p - (char*)d_ws) > ws_size) return;  // insufficient workspace

  // y_rows aliases w1t: w1t is only read by gemm1, which completes before
  // gemm2 writes y (same stream). 33.5 MB <= 67 MB region.
  unsigned short* y = w1t;

  hipMemsetAsync(ctrl, 0, 1024, stream);

  setup_kernel<<<2048 + 8192 + 8192, 256, 0, stream>>>(
      x, Wr, br, ctrl, tope, topw, xb, W1, W2, w1t, w2t);
  place_kernel<<<T_TOKENS / 256, 256, 0, stream>>>(tope, topw, ctrl, rowlist, posmap);
  gemm1_kernel<<<dim3(DF / 128, 64, NE), 256, 0, stream>>>(xb, w1t, b1, ctrl, rowlist, h);
  gemm2_kernel<<<dim3(64, DM / 256, NE), 256, 0, stream>>>(h, w2t, b2, ctrl, y);
  combine_kernel<<<T_TOKENS, 256, 0, stream>>>(y, posmap, topw, out);
}